// Round 1
// 251.761 us; speedup vs baseline: 1.0451x; 1.0451x over previous
//
#include <hip/hip_runtime.h>

// SAGEConv: out = h@W_self.T + b_self + b_nb + segsum(val * (h@W_nb.T)[col])
// R10: (a) gemm: persistent blocks (grid 512 = 2 blocks/CU exactly), each
//     block pipelines ~3 tiles with rolling register prefetch + LDS double
//     buffer -> global loads stay in flight across nearly the whole block
//     lifetime (was: 45% dead time with TPB=2 -> 1.9 TB/s duty-limited).
//     (b) aggregate: single 25000-block launch (was 2x12500) + gather unroll
//     4->8 for 2x memory-level parallelism on the L3-bound tmpb gather.

constexpr int NN = 100000;
constexpr int NE = 1600000;
constexpr int D  = 128;
constexpr int NBUCK  = 500;                // buckets of BROWS rows
constexpr int BROWS  = 200;                // 500*200 = 100000 exactly
constexpr int BCAP   = 3584;               // mean 3200 + ~7 sigma
constexpr int CHUNK  = 2048;               // edges per wc_scatter workgroup
constexpr int NCH    = (NE + CHUNK - 1) / CHUNK;   // 782
constexpr int GM     = 64;                 // gemm M-tile rows
constexpr int NT     = (NN + GM - 1) / GM; // 1563 tiles total
constexpr int GRID   = 512;                // persistent gemm blocks (2/CU)
constexpr int LP     = 132;                // LDS bf16 pitch (2-way = free)

typedef __bf16 bf16x8 __attribute__((ext_vector_type(8)));
typedef float  f32x4  __attribute__((ext_vector_type(4)));
typedef float  f32x2  __attribute__((ext_vector_type(2)));
typedef unsigned short u16x4 __attribute__((ext_vector_type(4)));

// ---------------- Dual GEMM (persistent, pipelined) ----------------
__global__ __launch_bounds__(256) void gemm_mfma(
    const float* __restrict__ h,
    const float* __restrict__ Wself,
    const float* __restrict__ Wnb,
    const float* __restrict__ bself,
    const float* __restrict__ bnb,
    float* __restrict__ out,
    __bf16* __restrict__ tmpb)
{
    __shared__ __bf16 hs[2][GM * LP];   // 2 x 16.9 KB
    const int t    = threadIdx.x;
    const int w    = t >> 6;
    const int lane = t & 63;
    const int l15  = lane & 15;
    const int quad = lane >> 4;

    // W frags (A operand): frag[ns][kk], m = w*64+ns*16+l15, k = quad*8+kk*32+j.
    bf16x8 wf[4][4];
    #pragma unroll
    for (int ns = 0; ns < 4; ++ns) {
        int wrow = w * 64 + ns * 16 + l15;
        const float* wr = (wrow < D) ? (Wself + (size_t)wrow * D)
                                     : (Wnb + (size_t)(wrow - D) * D);
        #pragma unroll
        for (int kk = 0; kk < 4; ++kk) {
            f32x4 lo = *(const f32x4*)(wr + kk * 32 + quad * 8);
            f32x4 hi = *(const f32x4*)(wr + kk * 32 + quad * 8 + 4);
            bf16x8 bb;
            #pragma unroll
            for (int j = 0; j < 4; ++j) { bb[j] = (__bf16)lo[j]; bb[4 + j] = (__bf16)hi[j]; }
            wf[ns][kk] = bb;
        }
    }
    // Bias vectors (cols ns*16+quad*4 .. +3), only used by waves 0,1.
    f32x4 biasv[4];
    #pragma unroll
    for (int ns = 0; ns < 4; ++ns) {
        int col = w * 64 + ns * 16 + quad * 4;
        if (col < D) {
            f32x4 b1 = *(const f32x4*)(bself + col);
            f32x4 b2 = *(const f32x4*)(bnb + col);
            biasv[ns] = b1 + b2;
        } else biasv[ns] = (f32x4){0.f, 0.f, 0.f, 0.f};
    }

    // Per-thread staging geometry (constant across tiles).
    // it-th chunk: idx = it*2048 + t*8 -> row = idx>>7, col = idx&127.
    int srow[4], scol[4];
    #pragma unroll
    for (int it = 0; it < 4; ++it) {
        int idx = it * 2048 + t * 8;
        srow[it] = idx >> 7;
        scol[it] = idx & 127;
    }

    // Prologue: stage first tile into hs[0].
    {
        const int row0 = blockIdx.x * GM;
        #pragma unroll
        for (int it = 0; it < 4; ++it) {
            int gr = row0 + srow[it]; if (gr >= NN) gr = NN - 1;
            f32x4 lo = *(const f32x4*)(h + (size_t)gr * D + scol[it]);
            f32x4 hi = *(const f32x4*)(h + (size_t)gr * D + scol[it] + 4);
            bf16x8 v;
            #pragma unroll
            for (int j = 0; j < 4; ++j) { v[j] = (__bf16)lo[j]; v[4 + j] = (__bf16)hi[j]; }
            *(bf16x8*)(&hs[0][srow[it] * LP + scol[it]]) = v;
        }
    }
    __syncthreads();

    int buf = 0;
    for (int tile = blockIdx.x; tile < NT; tile += GRID) {
        const int row0 = tile * GM;
        const bool hasn = (tile + GRID) < NT;

        // Issue next tile's global loads NOW (in flight across the MFMA
        // compute below).
        f32x4 pf[8];
        if (hasn) {
            const int nrow0 = (tile + GRID) * GM;
            #pragma unroll
            for (int it = 0; it < 4; ++it) {
                int gr = nrow0 + srow[it]; if (gr >= NN) gr = NN - 1;
                pf[it * 2]     = *(const f32x4*)(h + (size_t)gr * D + scol[it]);
                pf[it * 2 + 1] = *(const f32x4*)(h + (size_t)gr * D + scol[it] + 4);
            }
        }

        // Compute: acc[mi][ns]; C-layout (swapped operands):
        //   C col(lane&15) = out-row = mi*16+l15 ; C row(quad*4+reg) = out-col.
        f32x4 acc[4][4];
        #pragma unroll
        for (int mi = 0; mi < 4; ++mi)
            #pragma unroll
            for (int ns = 0; ns < 4; ++ns) acc[mi][ns] = (f32x4){0.f, 0.f, 0.f, 0.f};

        const __bf16* hb = hs[buf];
        #pragma unroll
        for (int mi = 0; mi < 4; ++mi) {
            bf16x8 hf[4];
            #pragma unroll
            for (int kk = 0; kk < 4; ++kk)
                hf[kk] = *(const bf16x8*)(&hb[(mi * 16 + l15) * LP + quad * 8 + kk * 32]);
            #pragma unroll
            for (int ns = 0; ns < 4; ++ns)
                #pragma unroll
                for (int kk = 0; kk < 4; ++kk)
                    acc[mi][ns] = __builtin_amdgcn_mfma_f32_16x16x32_bf16(wf[ns][kk], hf[kk], acc[mi][ns], 0, 0, 0);
        }

        // Convert + write the prefetched tile into the other LDS buffer.
        // Safe with one barrier/iter: hs[buf^1] was last read before the
        // previous iteration's barrier.
        if (hasn) {
            #pragma unroll
            for (int it = 0; it < 4; ++it) {
                bf16x8 v;
                #pragma unroll
                for (int j = 0; j < 4; ++j) {
                    v[j]     = (__bf16)pf[it * 2][j];
                    v[4 + j] = (__bf16)pf[it * 2 + 1][j];
                }
                *(bf16x8*)(&hs[buf ^ 1][srow[it] * LP + scol[it]]) = v;
            }
        }
        __syncthreads();

        // Epilogue: packed stores, overlaps other waves' next-tile compute.
        #pragma unroll
        for (int mi = 0; mi < 4; ++mi) {
            int row = row0 + mi * 16 + l15;
            if (row < NN) {
                if (w < 2) {
                    #pragma unroll
                    for (int ns = 0; ns < 4; ++ns) {
                        int col = w * 64 + ns * 16 + quad * 4;
                        *(f32x4*)(out + (size_t)row * D + col) = acc[mi][ns] + biasv[ns];
                    }
                } else {
                    #pragma unroll
                    for (int ns = 0; ns < 4; ++ns) {
                        int col = (w - 2) * 64 + ns * 16 + quad * 4;
                        u16x4 v;
                        #pragma unroll
                        for (int i = 0; i < 4; ++i) {
                            __bf16 b = (__bf16)acc[mi][ns][i];
                            v[i] = *(unsigned short*)&b;
                        }
                        *(u16x4*)(tmpb + (size_t)row * D + col) = v;
                    }
                }
            }
        }
        buf ^= 1;
    }
}

// ---------------- Write-combined bucket scatter (500 bins, CHUNK 2048) --
__global__ __launch_bounds__(256) void wc_scatter(
    const int* __restrict__ erow, const int* __restrict__ ecol,
    const float* __restrict__ eval_,
    int* __restrict__ gcount, int2* __restrict__ epair)
{
    __shared__ int  cnt[NBUCK];
    __shared__ int  lscan[NBUCK];
    __shared__ int  gbase[NBUCK];
    __shared__ int  ss[512];
    __shared__ int2 sbuf[CHUNK];
    __shared__ int  saddr[CHUNK];
    __shared__ int  s_total;

    const int t  = threadIdx.x;
    const int c0 = blockIdx.x * CHUNK;

    for (int b = t; b < NBUCK; b += 256) cnt[b] = 0;
    __syncthreads();

    int   bp[8];       // b | rlo<<9 | pos<<17  (or -1 if OOB)
    int   colr[8];
    float valr[8];
    #pragma unroll
    for (int j = 0; j < 8; ++j) {
        int e = c0 + j * 256 + t;
        if (e < NE) {
            int r   = erow[e];
            colr[j] = ecol[e];
            valr[j] = eval_[e];
            int b   = r / BROWS;
            int rlo = r - b * BROWS;
            int pos = atomicAdd(&cnt[b], 1);
            bp[j]   = b | (rlo << 9) | (pos << 17);
        } else bp[j] = -1;
    }
    __syncthreads();

    // Scan 512 slots with 256 threads (2/thread).
    ss[t]       = (t < NBUCK)       ? cnt[t]       : 0;
    ss[t + 256] = (t + 256 < NBUCK) ? cnt[t + 256] : 0;
    __syncthreads();
    for (int off = 1; off < 512; off <<= 1) {
        int i0 = t, i1 = t + 256;
        int r0 = ss[i0] + ((i0 >= off) ? ss[i0 - off] : 0);
        int r1 = ss[i1] + ((i1 >= off) ? ss[i1 - off] : 0);
        __syncthreads();
        ss[i0] = r0; ss[i1] = r1;
        __syncthreads();
    }
    if (t < NBUCK) {
        int n = cnt[t];
        lscan[t] = ss[t] - n;
        gbase[t] = (n > 0) ? atomicAdd(&gcount[t], n) : 0;
    }
    if (t + 256 < NBUCK) {
        int n = cnt[t + 256];
        lscan[t + 256] = ss[t + 256] - n;
        gbase[t + 256] = (n > 0) ? atomicAdd(&gcount[t + 256], n) : 0;
    }
    if (t == 0) s_total = ss[511];
    __syncthreads();

    #pragma unroll
    for (int j = 0; j < 8; ++j) {
        if (bp[j] >= 0) {
            int b   = bp[j] & 511;
            int rlo = (bp[j] >> 9) & 255;
            int pos = bp[j] >> 17;
            int slot = lscan[b] + pos;
            sbuf[slot]  = make_int2(colr[j] | (rlo << 17), __float_as_int(valr[j]));
            saddr[slot] = b * BCAP + gbase[b] + pos;
        }
    }
    __syncthreads();

    int ce = s_total;
    for (int i = t; i < ce; i += 256)
        epair[saddr[i]] = sbuf[i];
}

// ---------------- Bucket sort (500 blocks, 512 thr) ---------------------
__global__ __launch_bounds__(512) void bucket_sort(
    const int2* __restrict__ epair, const int* __restrict__ gcount,
    int2* __restrict__ epair2, int2* __restrict__ rowrange)
{
    __shared__ int  cnt[BROWS];
    __shared__ int  off2[BROWS];
    __shared__ int  cur[BROWS];
    __shared__ int  ss[256];
    __shared__ int2 sorted[BCAP];

    const int t = threadIdx.x;
    const int b = blockIdx.x;
    const int n = gcount[b];
    const int2* src = epair + (size_t)b * BCAP;

    if (t < BROWS) cnt[t] = 0;
    __syncthreads();

    int2 r[8];
    int  nr = 0;
    for (int i = t; i < n; i += 512) {
        int2 p = src[i];
        r[nr++] = p;
        atomicAdd(&cnt[(p.x >> 17) & 255], 1);
    }
    __syncthreads();

    if (t < 256) ss[t] = (t < BROWS) ? cnt[t] : 0;
    __syncthreads();
    for (int o = 1; o < 256; o <<= 1) {
        int y = 0;
        if (t < 256 && t >= o) y = ss[t - o];
        __syncthreads();
        if (t < 256) ss[t] += y;
        __syncthreads();
    }
    if (t < BROWS) {
        int v = cnt[t];
        off2[t] = ss[t] - v;
        cur[t]  = ss[t] - v;
    }
    __syncthreads();

    for (int j = 0; j < nr; ++j) {
        int slot = atomicAdd(&cur[(r[j].x >> 17) & 255], 1);
        sorted[slot] = r[j];
    }
    __syncthreads();

    const int base = b * BCAP;
    for (int i = t; i < n; i += 512)
        epair2[base + i] = sorted[i];
    if (t < BROWS) {
        int row = b * BROWS + t;
        if (row < NN)
            rowrange[row] = make_int2(base + off2[t], base + off2[t] + cnt[t]);
    }
}

// ---------------- Aggregate: one wave per row, 8-deep gather MLP --------
__global__ __launch_bounds__(256) void aggregate(
    const __bf16* __restrict__ tmpb, const int2* __restrict__ rowrange,
    const int2* __restrict__ epair2, float* __restrict__ out,
    int row0, int nrows)
{
    int wave = row0 + ((blockIdx.x * 256 + threadIdx.x) >> 6);
    if (wave >= row0 + nrows) return;
    int lane = threadIdx.x & 63;
    int2 rr = rowrange[wave];
    int beg = __builtin_amdgcn_readfirstlane(rr.x);
    int end = __builtin_amdgcn_readfirstlane(rr.y);

    float ax[4] = {0.f, 0.f, 0.f, 0.f};
    float ay[4] = {0.f, 0.f, 0.f, 0.f};
    int e = beg;
    for (; e + 7 < end; e += 8) {
        int2 p[8];
        #pragma unroll
        for (int k = 0; k < 8; ++k) p[k] = epair2[e + k];
        #pragma unroll
        for (int k = 0; k < 8; ++k) {
            int col = p[k].x & 0x1FFFF;
            unsigned u = *(const unsigned*)(tmpb + (size_t)col * D + lane * 2);
            float v = __int_as_float(p[k].y);
            ax[k & 3] += v * __uint_as_float(u << 16);
            ay[k & 3] += v * __uint_as_float(u & 0xffff0000u);
        }
    }
    for (; e + 3 < end; e += 4) {
        int2 p[4];
        #pragma unroll
        for (int k = 0; k < 4; ++k) p[k] = epair2[e + k];
        #pragma unroll
        for (int k = 0; k < 4; ++k) {
            int col = p[k].x & 0x1FFFF;
            unsigned u = *(const unsigned*)(tmpb + (size_t)col * D + lane * 2);
            float v = __int_as_float(p[k].y);
            ax[k] += v * __uint_as_float(u << 16);
            ay[k] += v * __uint_as_float(u & 0xffff0000u);
        }
    }
    for (; e < end; ++e) {
        int2 p = epair2[e];
        int col = p.x & 0x1FFFF;
        unsigned u = *(const unsigned*)(tmpb + (size_t)col * D + lane * 2);
        float v = __int_as_float(p.y);
        ax[0] += v * __uint_as_float(u << 16);
        ay[0] += v * __uint_as_float(u & 0xffff0000u);
    }
    f32x2* o = (f32x2*)(out + (size_t)wave * D + lane * 2);
    f32x2 c = __builtin_nontemporal_load(o);
    c.x += (ax[0] + ax[1]) + (ax[2] + ax[3]);
    c.y += (ay[0] + ay[1]) + (ay[2] + ay[3]);
    __builtin_nontemporal_store(c, o);
}

extern "C" void kernel_launch(void* const* d_in, const int* in_sizes, int n_in,
                              void* d_out, int out_size, void* d_ws, size_t ws_size,
                              hipStream_t stream) {
    const float* h     = (const float*)d_in[0];
    const float* eval_ = (const float*)d_in[1];
    const float* Wself = (const float*)d_in[2];
    const float* bself = (const float*)d_in[3];
    const float* Wnb   = (const float*)d_in[4];
    const float* bnb   = (const float*)d_in[5];
    const int*   erow  = (const int*)d_in[6];
    const int*   ecol  = (const int*)d_in[7];
    float* out = (float*)d_out;

    // ws: tmpb 25.6MB | epair 14.3MB | epair2 14.3MB | rowrange 800KB | gcount
    char* p = (char*)d_ws;
    __bf16* tmpb    = (__bf16*)p;   p += (size_t)NT * GM * D * 2;
    int2*   epair   = (int2*)p;     p += (size_t)NBUCK * BCAP * 8;
    int2*   epair2  = (int2*)p;     p += (size_t)NBUCK * BCAP * 8;
    int2*   rowrange= (int2*)p;     p += (size_t)NN * 8;
    int*    gcount  = (int*)p;

    hipMemsetAsync(gcount, 0, NBUCK * 4, stream);

    gemm_mfma<<<GRID, 256, 0, stream>>>(h, Wself, Wnb, bself, bnb, out, tmpb);
    wc_scatter<<<NCH, 256, 0, stream>>>(erow, ecol, eval_, gcount, epair);
    bucket_sort<<<NBUCK, 512, 0, stream>>>(epair, gcount, epair2, rowrange);
    aggregate<<<(NN * 64) / 256, 256, 0, stream>>>(tmpb, rowrange, epair2, out, 0, NN);
}

// Round 2
// 250.823 us; speedup vs baseline: 1.0490x; 1.0037x over previous
//
#include <hip/hip_runtime.h>

// SAGEConv: out = h@W_self.T + b_self + b_nb + segsum(val * (h@W_nb.T)[col])
// R11: fuse bucket_sort + aggregate into one kernel (sort_aggregate):
//     the sorted bucket already lives in LDS after the counting sort --
//     aggregate straight from it. Removes epair2 write+read (25.6 MB),
//     rowrange (1.6 MB), one dependent launch, and the sort's store/reload
//     latency. gemm (persistent pipelined) and wc_scatter unchanged.

constexpr int NN = 100000;
constexpr int NE = 1600000;
constexpr int D  = 128;
constexpr int NBUCK  = 500;                // buckets of BROWS rows
constexpr int BROWS  = 200;                // 500*200 = 100000 exactly
constexpr int BCAP   = 3584;               // mean 3200 + ~7 sigma
constexpr int CHUNK  = 2048;               // edges per wc_scatter workgroup
constexpr int NCH    = (NE + CHUNK - 1) / CHUNK;   // 782
constexpr int GM     = 64;                 // gemm M-tile rows
constexpr int NT     = (NN + GM - 1) / GM; // 1563 tiles total
constexpr int GRID   = 512;                // persistent gemm blocks (2/CU)
constexpr int LP     = 132;                // LDS bf16 pitch (2-way = free)

typedef __bf16 bf16x8 __attribute__((ext_vector_type(8)));
typedef float  f32x4  __attribute__((ext_vector_type(4)));
typedef float  f32x2  __attribute__((ext_vector_type(2)));
typedef unsigned short u16x4 __attribute__((ext_vector_type(4)));

// ---------------- Dual GEMM (persistent, pipelined) ----------------
__global__ __launch_bounds__(256) void gemm_mfma(
    const float* __restrict__ h,
    const float* __restrict__ Wself,
    const float* __restrict__ Wnb,
    const float* __restrict__ bself,
    const float* __restrict__ bnb,
    float* __restrict__ out,
    __bf16* __restrict__ tmpb)
{
    __shared__ __bf16 hs[2][GM * LP];   // 2 x 16.9 KB
    const int t    = threadIdx.x;
    const int w    = t >> 6;
    const int lane = t & 63;
    const int l15  = lane & 15;
    const int quad = lane >> 4;

    // W frags (A operand): frag[ns][kk], m = w*64+ns*16+l15, k = quad*8+kk*32+j.
    bf16x8 wf[4][4];
    #pragma unroll
    for (int ns = 0; ns < 4; ++ns) {
        int wrow = w * 64 + ns * 16 + l15;
        const float* wr = (wrow < D) ? (Wself + (size_t)wrow * D)
                                     : (Wnb + (size_t)(wrow - D) * D);
        #pragma unroll
        for (int kk = 0; kk < 4; ++kk) {
            f32x4 lo = *(const f32x4*)(wr + kk * 32 + quad * 8);
            f32x4 hi = *(const f32x4*)(wr + kk * 32 + quad * 8 + 4);
            bf16x8 bb;
            #pragma unroll
            for (int j = 0; j < 4; ++j) { bb[j] = (__bf16)lo[j]; bb[4 + j] = (__bf16)hi[j]; }
            wf[ns][kk] = bb;
        }
    }
    // Bias vectors (cols ns*16+quad*4 .. +3), only used by waves 0,1.
    f32x4 biasv[4];
    #pragma unroll
    for (int ns = 0; ns < 4; ++ns) {
        int col = w * 64 + ns * 16 + quad * 4;
        if (col < D) {
            f32x4 b1 = *(const f32x4*)(bself + col);
            f32x4 b2 = *(const f32x4*)(bnb + col);
            biasv[ns] = b1 + b2;
        } else biasv[ns] = (f32x4){0.f, 0.f, 0.f, 0.f};
    }

    // Per-thread staging geometry (constant across tiles).
    int srow[4], scol[4];
    #pragma unroll
    for (int it = 0; it < 4; ++it) {
        int idx = it * 2048 + t * 8;
        srow[it] = idx >> 7;
        scol[it] = idx & 127;
    }

    // Prologue: stage first tile into hs[0].
    {
        const int row0 = blockIdx.x * GM;
        #pragma unroll
        for (int it = 0; it < 4; ++it) {
            int gr = row0 + srow[it]; if (gr >= NN) gr = NN - 1;
            f32x4 lo = *(const f32x4*)(h + (size_t)gr * D + scol[it]);
            f32x4 hi = *(const f32x4*)(h + (size_t)gr * D + scol[it] + 4);
            bf16x8 v;
            #pragma unroll
            for (int j = 0; j < 4; ++j) { v[j] = (__bf16)lo[j]; v[4 + j] = (__bf16)hi[j]; }
            *(bf16x8*)(&hs[0][srow[it] * LP + scol[it]]) = v;
        }
    }
    __syncthreads();

    int buf = 0;
    for (int tile = blockIdx.x; tile < NT; tile += GRID) {
        const int row0 = tile * GM;
        const bool hasn = (tile + GRID) < NT;

        // Issue next tile's global loads NOW (in flight across the MFMA
        // compute below).
        f32x4 pf[8];
        if (hasn) {
            const int nrow0 = (tile + GRID) * GM;
            #pragma unroll
            for (int it = 0; it < 4; ++it) {
                int gr = nrow0 + srow[it]; if (gr >= NN) gr = NN - 1;
                pf[it * 2]     = *(const f32x4*)(h + (size_t)gr * D + scol[it]);
                pf[it * 2 + 1] = *(const f32x4*)(h + (size_t)gr * D + scol[it] + 4);
            }
        }

        // Compute: acc[mi][ns]; C-layout (swapped operands):
        //   C col(lane&15) = out-row = mi*16+l15 ; C row(quad*4+reg) = out-col.
        f32x4 acc[4][4];
        #pragma unroll
        for (int mi = 0; mi < 4; ++mi)
            #pragma unroll
            for (int ns = 0; ns < 4; ++ns) acc[mi][ns] = (f32x4){0.f, 0.f, 0.f, 0.f};

        const __bf16* hb = hs[buf];
        #pragma unroll
        for (int mi = 0; mi < 4; ++mi) {
            bf16x8 hf[4];
            #pragma unroll
            for (int kk = 0; kk < 4; ++kk)
                hf[kk] = *(const bf16x8*)(&hb[(mi * 16 + l15) * LP + quad * 8 + kk * 32]);
            #pragma unroll
            for (int ns = 0; ns < 4; ++ns)
                #pragma unroll
                for (int kk = 0; kk < 4; ++kk)
                    acc[mi][ns] = __builtin_amdgcn_mfma_f32_16x16x32_bf16(wf[ns][kk], hf[kk], acc[mi][ns], 0, 0, 0);
        }

        // Convert + write the prefetched tile into the other LDS buffer.
        if (hasn) {
            #pragma unroll
            for (int it = 0; it < 4; ++it) {
                bf16x8 v;
                #pragma unroll
                for (int j = 0; j < 4; ++j) {
                    v[j]     = (__bf16)pf[it * 2][j];
                    v[4 + j] = (__bf16)pf[it * 2 + 1][j];
                }
                *(bf16x8*)(&hs[buf ^ 1][srow[it] * LP + scol[it]]) = v;
            }
        }
        __syncthreads();

        // Epilogue: packed stores, overlaps other waves' next-tile compute.
        #pragma unroll
        for (int mi = 0; mi < 4; ++mi) {
            int row = row0 + mi * 16 + l15;
            if (row < NN) {
                if (w < 2) {
                    #pragma unroll
                    for (int ns = 0; ns < 4; ++ns) {
                        int col = w * 64 + ns * 16 + quad * 4;
                        *(f32x4*)(out + (size_t)row * D + col) = acc[mi][ns] + biasv[ns];
                    }
                } else {
                    #pragma unroll
                    for (int ns = 0; ns < 4; ++ns) {
                        int col = (w - 2) * 64 + ns * 16 + quad * 4;
                        u16x4 v;
                        #pragma unroll
                        for (int i = 0; i < 4; ++i) {
                            __bf16 b = (__bf16)acc[mi][ns][i];
                            v[i] = *(unsigned short*)&b;
                        }
                        *(u16x4*)(tmpb + (size_t)row * D + col) = v;
                    }
                }
            }
        }
        buf ^= 1;
    }
}

// ---------------- Write-combined bucket scatter (500 bins, CHUNK 2048) --
__global__ __launch_bounds__(256) void wc_scatter(
    const int* __restrict__ erow, const int* __restrict__ ecol,
    const float* __restrict__ eval_,
    int* __restrict__ gcount, int2* __restrict__ epair)
{
    __shared__ int  cnt[NBUCK];
    __shared__ int  lscan[NBUCK];
    __shared__ int  gbase[NBUCK];
    __shared__ int  ss[512];
    __shared__ int2 sbuf[CHUNK];
    __shared__ int  saddr[CHUNK];
    __shared__ int  s_total;

    const int t  = threadIdx.x;
    const int c0 = blockIdx.x * CHUNK;

    for (int b = t; b < NBUCK; b += 256) cnt[b] = 0;
    __syncthreads();

    int   bp[8];       // b | rlo<<9 | pos<<17  (or -1 if OOB)
    int   colr[8];
    float valr[8];
    #pragma unroll
    for (int j = 0; j < 8; ++j) {
        int e = c0 + j * 256 + t;
        if (e < NE) {
            int r   = erow[e];
            colr[j] = ecol[e];
            valr[j] = eval_[e];
            int b   = r / BROWS;
            int rlo = r - b * BROWS;
            int pos = atomicAdd(&cnt[b], 1);
            bp[j]   = b | (rlo << 9) | (pos << 17);
        } else bp[j] = -1;
    }
    __syncthreads();

    // Scan 512 slots with 256 threads (2/thread).
    ss[t]       = (t < NBUCK)       ? cnt[t]       : 0;
    ss[t + 256] = (t + 256 < NBUCK) ? cnt[t + 256] : 0;
    __syncthreads();
    for (int off = 1; off < 512; off <<= 1) {
        int i0 = t, i1 = t + 256;
        int r0 = ss[i0] + ((i0 >= off) ? ss[i0 - off] : 0);
        int r1 = ss[i1] + ((i1 >= off) ? ss[i1 - off] : 0);
        __syncthreads();
        ss[i0] = r0; ss[i1] = r1;
        __syncthreads();
    }
    if (t < NBUCK) {
        int n = cnt[t];
        lscan[t] = ss[t] - n;
        gbase[t] = (n > 0) ? atomicAdd(&gcount[t], n) : 0;
    }
    if (t + 256 < NBUCK) {
        int n = cnt[t + 256];
        lscan[t + 256] = ss[t + 256] - n;
        gbase[t + 256] = (n > 0) ? atomicAdd(&gcount[t + 256], n) : 0;
    }
    if (t == 0) s_total = ss[511];
    __syncthreads();

    #pragma unroll
    for (int j = 0; j < 8; ++j) {
        if (bp[j] >= 0) {
            int b   = bp[j] & 511;
            int rlo = (bp[j] >> 9) & 255;
            int pos = bp[j] >> 17;
            int slot = lscan[b] + pos;
            sbuf[slot]  = make_int2(colr[j] | (rlo << 17), __float_as_int(valr[j]));
            saddr[slot] = b * BCAP + gbase[b] + pos;
        }
    }
    __syncthreads();

    int ce = s_total;
    for (int i = t; i < ce; i += 256)
        epair[saddr[i]] = sbuf[i];
}

// ---------------- Fused bucket sort + aggregate (500 blocks, 512 thr) ---
// Counting-sort the bucket's edges into LDS, then aggregate straight from
// LDS: wave wv handles rows [wv*25, wv*25+25) of the bucket.
__global__ __launch_bounds__(512, 4) void sort_aggregate(
    const int2* __restrict__ epair, const int* __restrict__ gcount,
    const __bf16* __restrict__ tmpb, float* __restrict__ out)
{
    __shared__ int  cnt[BROWS];
    __shared__ int  off2[BROWS];
    __shared__ int  cur[BROWS];
    __shared__ int  ss[256];
    __shared__ int2 sorted[BCAP];

    const int t = threadIdx.x;
    const int b = blockIdx.x;
    const int n = gcount[b];
    const int2* src = epair + (size_t)b * BCAP;

    if (t < BROWS) cnt[t] = 0;
    __syncthreads();

    int2 r[8];
    int  nr = 0;
    for (int i = t; i < n; i += 512) {
        int2 p = src[i];
        r[nr++] = p;
        atomicAdd(&cnt[(p.x >> 17) & 255], 1);
    }
    __syncthreads();

    if (t < 256) ss[t] = (t < BROWS) ? cnt[t] : 0;
    __syncthreads();
    for (int o = 1; o < 256; o <<= 1) {
        int y = 0;
        if (t < 256 && t >= o) y = ss[t - o];
        __syncthreads();
        if (t < 256) ss[t] += y;
        __syncthreads();
    }
    if (t < BROWS) {
        int v = cnt[t];
        off2[t] = ss[t] - v;
        cur[t]  = ss[t] - v;
    }
    __syncthreads();

    for (int j = 0; j < nr; ++j) {
        int slot = atomicAdd(&cur[(r[j].x >> 17) & 255], 1);
        sorted[slot] = r[j];
    }
    __syncthreads();
    // Now: row rl's edges are sorted[off2[rl] .. cur[rl]) (cur==off2+cnt).

    // ---- Aggregate phase: 8 waves x 25 rows, gather tmpb, RMW out. ----
    const int wv   = t >> 6;
    const int lane = t & 63;
    const __bf16* tb = tmpb + lane * 2;

    for (int rl = wv * 25; rl < wv * 25 + 25; ++rl) {
        int beg = __builtin_amdgcn_readfirstlane(off2[rl]);
        int end = __builtin_amdgcn_readfirstlane(cur[rl]);
        if (beg >= end) continue;

        float ax[4] = {0.f, 0.f, 0.f, 0.f};
        float ay[4] = {0.f, 0.f, 0.f, 0.f};
        int e = beg;
        for (; e + 7 < end; e += 8) {
            int2 p[8];
            #pragma unroll
            for (int k = 0; k < 8; ++k) p[k] = sorted[e + k];
            #pragma unroll
            for (int k = 0; k < 8; ++k) {
                int col = p[k].x & 0x1FFFF;
                unsigned u = *(const unsigned*)(tb + (size_t)col * D);
                float v = __int_as_float(p[k].y);
                ax[k & 3] += v * __uint_as_float(u << 16);
                ay[k & 3] += v * __uint_as_float(u & 0xffff0000u);
            }
        }
        for (; e + 3 < end; e += 4) {
            int2 p[4];
            #pragma unroll
            for (int k = 0; k < 4; ++k) p[k] = sorted[e + k];
            #pragma unroll
            for (int k = 0; k < 4; ++k) {
                int col = p[k].x & 0x1FFFF;
                unsigned u = *(const unsigned*)(tb + (size_t)col * D);
                float v = __int_as_float(p[k].y);
                ax[k] += v * __uint_as_float(u << 16);
                ay[k] += v * __uint_as_float(u & 0xffff0000u);
            }
        }
        for (; e < end; ++e) {
            int2 p = sorted[e];
            int col = p.x & 0x1FFFF;
            unsigned u = *(const unsigned*)(tb + (size_t)col * D);
            float v = __int_as_float(p.y);
            ax[0] += v * __uint_as_float(u << 16);
            ay[0] += v * __uint_as_float(u & 0xffff0000u);
        }

        int row = b * BROWS + rl;
        f32x2* o = (f32x2*)(out + (size_t)row * D + lane * 2);
        f32x2 c = __builtin_nontemporal_load(o);
        c.x += (ax[0] + ax[1]) + (ax[2] + ax[3]);
        c.y += (ay[0] + ay[1]) + (ay[2] + ay[3]);
        __builtin_nontemporal_store(c, o);
    }
}

extern "C" void kernel_launch(void* const* d_in, const int* in_sizes, int n_in,
                              void* d_out, int out_size, void* d_ws, size_t ws_size,
                              hipStream_t stream) {
    const float* h     = (const float*)d_in[0];
    const float* eval_ = (const float*)d_in[1];
    const float* Wself = (const float*)d_in[2];
    const float* bself = (const float*)d_in[3];
    const float* Wnb   = (const float*)d_in[4];
    const float* bnb   = (const float*)d_in[5];
    const int*   erow  = (const int*)d_in[6];
    const int*   ecol  = (const int*)d_in[7];
    float* out = (float*)d_out;

    // ws: tmpb 25.6MB | epair 14.3MB | gcount
    char* p = (char*)d_ws;
    __bf16* tmpb    = (__bf16*)p;   p += (size_t)NT * GM * D * 2;
    int2*   epair   = (int2*)p;     p += (size_t)NBUCK * BCAP * 8;
    int*    gcount  = (int*)p;

    hipMemsetAsync(gcount, 0, NBUCK * 4, stream);

    gemm_mfma<<<GRID, 256, 0, stream>>>(h, Wself, Wnb, bself, bnb, out, tmpb);
    wc_scatter<<<NCH, 256, 0, stream>>>(erow, ecol, eval_, gcount, epair);
    sort_aggregate<<<NBUCK, 512, 0, stream>>>(epair, gcount, tmpb, out);
}